// Round 8
// baseline (46.181 us; speedup 1.0000x reference)
//
#include <hip/hip_runtime.h>
#include <float.h>

// PointGroup R8: R7 + final micro-trims, with pre-commitment: <5% gain here
// means the random-row gather pattern ceiling is reached (FETCH is compulsory,
// occupancy maxed, R6 proved MLP-saturated).
// - s_pack sentinel-padded by 8 -> chunk loads need no min-clamps.
// - parallel (lane-shuffle) scan of per-wave totals instead of tid==0 loop.

constexpr int kC    = 32;
constexpr int kFS   = 14;
constexpr int kNVOX = kFS * kFS * kFS;  // 2744
constexpr int kBLK  = 1024;
constexpr int kW    = kBLK / 64;        // 16 waves
constexpr int kPPT  = 2;                // points per thread (2048/1024)
constexpr int kPTS  = 2048;
constexpr int kCPT  = (kNVOX + kBLK - 1) / kBLK;  // 3 voxels per thread (scan)
constexpr int kGPW  = 16;               // points-window per group

__device__ inline float wsum(float v) {
#pragma unroll
  for (int o = 32; o; o >>= 1) v += __shfl_down(v, o);
  return v;
}
__device__ inline float wmin(float v) {
#pragma unroll
  for (int o = 32; o; o >>= 1) v = fminf(v, __shfl_down(v, o));
  return v;
}
__device__ inline float wmax(float v) {
#pragma unroll
  for (int o = 32; o; o >>= 1) v = fmaxf(v, __shfl_down(v, o));
  return v;
}

__global__ __launch_bounds__(kBLK, 8) void pg_kernel(
    const float* __restrict__ feats, const float* __restrict__ coords,
    const float* __restrict__ W, const float* __restrict__ bias,
    const float* __restrict__ rand3, const int* __restrict__ cidx,
    const int* __restrict__ coff, float* __restrict__ out) {
  __shared__ int s_cnt[kNVOX];
  __shared__ int s_off[kNVOX];          // after scatter: per-voxel END position
  __shared__ float s_rinv[kNVOX];       // 1/cnt per voxel
  __shared__ unsigned s_pack[kPTS + 8]; // (vid<<20)|pid; +8 sentinel pad
  __shared__ float s_red[kW * 9];
  __shared__ float s_redmax[kW * kC];
  __shared__ float s_bcast[7];
  __shared__ int s_wt[kW];

  const int c = blockIdx.x;
  const int tid = threadIdx.x;
  const int lane = tid & 63, wave = tid >> 6;
  const int start = coff[c], end = coff[c + 1];
  const int npts = end - start;

  // ---- Phase A: gather coords, reduce sum/min/max ----
  int pt[kPPT];
  float px[kPPT], py[kPPT], pz[kPPT];
  float sx = 0.f, sy = 0.f, sz = 0.f;
  float mnx = FLT_MAX, mny = FLT_MAX, mnz = FLT_MAX;
  float mxx = -FLT_MAX, mxy = -FLT_MAX, mxz = -FLT_MAX;
#pragma unroll
  for (int k = 0; k < kPPT; k++) {
    int i = start + tid + k * kBLK;
    if (i < end) {
      int p = cidx[2 * i + 1];
      pt[k] = p;
      float x = coords[3 * p + 0], y = coords[3 * p + 1], z = coords[3 * p + 2];
      px[k] = x; py[k] = y; pz[k] = z;
      sx += x; sy += y; sz += z;
      mnx = fminf(mnx, x); mny = fminf(mny, y); mnz = fminf(mnz, z);
      mxx = fmaxf(mxx, x); mxy = fmaxf(mxy, y); mxz = fmaxf(mxz, z);
    } else {
      pt[k] = -1;
    }
  }
  sx = wsum(sx); sy = wsum(sy); sz = wsum(sz);
  mnx = wmin(mnx); mny = wmin(mny); mnz = wmin(mnz);
  mxx = wmax(mxx); mxy = wmax(mxy); mxz = wmax(mxz);
  if (lane == 0) {
    float* r = &s_red[wave * 9];
    r[0] = sx; r[1] = sy; r[2] = sz;
    r[3] = mnx; r[4] = mny; r[5] = mnz;
    r[6] = mxx; r[7] = mxy; r[8] = mxz;
  }
  __syncthreads();
  if (tid == 0) {
    float Sx = s_red[0], Sy = s_red[1], Sz = s_red[2];
    float Mnx = s_red[3], Mny = s_red[4], Mnz = s_red[5];
    float Mxx = s_red[6], Mxy = s_red[7], Mxz = s_red[8];
    for (int w = 1; w < kW; w++) {
      const float* r = &s_red[w * 9];
      Sx += r[0]; Sy += r[1]; Sz += r[2];
      Mnx = fminf(Mnx, r[3]); Mny = fminf(Mny, r[4]); Mnz = fminf(Mnz, r[5]);
      Mxx = fmaxf(Mxx, r[6]); Mxy = fmaxf(Mxy, r[7]); Mxz = fmaxf(Mxz, r[8]);
    }
    float n = (float)npts;
    float cmx = Sx / n, cmy = Sy / n, cmz = Sz / n;
    float cminx = Mnx - cmx, cminy = Mny - cmy, cminz = Mnz - cmz;
    float cmaxx = Mxx - cmx, cmaxy = Mxy - cmy, cmaxz = Mxz - cmz;
    float r0 = (cmaxx - cminx) / 14.0f;
    float r1 = (cmaxy - cminy) / 14.0f;
    float r2 = (cmaxz - cminz) / 14.0f;
    float cs = 1.0f / fmaxf(fmaxf(r0, r1), r2) - 0.01f;
    cs = fminf(cs, 50.0f);
    float r3x = rand3[0], r3y = rand3[1], r3z = rand3[2];
    float mn0 = cminx * cs, mx0 = cmaxx * cs, b0 = mx0 - mn0;
    float mn1 = cminy * cs, mx1 = cmaxy * cs, b1 = mx1 - mn1;
    float mn2 = cminz * cs, mx2 = cmaxz * cs, b2 = mx2 - mn2;
    float ox = -mn0 + fmaxf(14.0f - b0 - 0.001f, 0.0f) * r3x +
               fminf(14.0f - b0 + 0.001f, 0.0f) * r3x;
    float oy = -mn1 + fmaxf(14.0f - b1 - 0.001f, 0.0f) * r3y +
               fminf(14.0f - b1 + 0.001f, 0.0f) * r3y;
    float oz = -mn2 + fmaxf(14.0f - b2 - 0.001f, 0.0f) * r3z +
               fminf(14.0f - b2 + 0.001f, 0.0f) * r3z;
    s_bcast[0] = cmx; s_bcast[1] = cmy; s_bcast[2] = cmz;
    s_bcast[3] = cs;
    s_bcast[4] = ox; s_bcast[5] = oy; s_bcast[6] = oz;
  }
  __syncthreads();
  const float cmx = s_bcast[0], cmy = s_bcast[1], cmz = s_bcast[2];
  const float cs = s_bcast[3];
  const float ox = s_bcast[4], oy = s_bcast[5], oz = s_bcast[6];

  // ---- voxel ids (reference FP op order) ----
  int vid[kPPT];
#pragma unroll
  for (int k = 0; k < kPPT; k++) {
    if (pt[k] >= 0) {
      float tx = (px[k] - cmx) * cs + ox;
      float ty = (py[k] - cmy) * cs + oy;
      float tz = (pz[k] - cmz) * cs + oz;
      int vx = min(kFS - 1, max(0, (int)floorf(tx)));
      int vy = min(kFS - 1, max(0, (int)floorf(ty)));
      int vz = min(kFS - 1, max(0, (int)floorf(tz)));
      vid[k] = (vx * kFS + vy) * kFS + vz;
    } else {
      vid[k] = -1;
    }
  }

  // ---- counting sort: counts (+ sentinel pad write) ----
  for (int v = tid; v < kNVOX; v += kBLK) s_cnt[v] = 0;
  if (tid < 8) s_pack[npts + tid] = 0u;  // pad: vid 0, pid 0 (guarded off)
  __syncthreads();
#pragma unroll
  for (int k = 0; k < kPPT; k++)
    if (vid[k] >= 0) atomicAdd(&s_cnt[vid[k]], 1);
  __syncthreads();

  // ---- exclusive prefix scan over s_cnt -> s_off; also fill s_rinv ----
  {
    const int base = tid * kCPT;
    int local[kCPT];
    int sum = 0;
#pragma unroll
    for (int j = 0; j < kCPT; j++) {
      int v = base + j;
      int x = (v < kNVOX) ? s_cnt[v] : 0;
      if (v < kNVOX) s_rinv[v] = (x > 0) ? (1.0f / (float)x) : 0.0f;
      local[j] = sum;
      sum += x;
    }
    int inc = sum;
#pragma unroll
    for (int o = 1; o < 64; o <<= 1) {
      int t = __shfl_up(inc, o);
      if (lane >= o) inc += t;
    }
    if (lane == 63) s_wt[wave] = inc;
    __syncthreads();
    if (tid < kW) {  // parallel exclusive scan of 16 wave totals (wave 0)
      int t = s_wt[tid];
      int v = t;
#pragma unroll
      for (int o = 1; o < kW; o <<= 1) {
        int u = __shfl_up(v, o);
        if (tid >= o) v += u;
      }
      s_wt[tid] = v - t;  // exclusive
    }
    __syncthreads();
    const int texcl = s_wt[wave] + inc - sum;
#pragma unroll
    for (int j = 0; j < kCPT; j++) {
      int v = base + j;
      if (v < kNVOX) s_off[v] = texcl + local[j];
    }
  }
  __syncthreads();

  // ---- scatter (s_off becomes per-voxel END); pack (vid<<20)|pid ----
#pragma unroll
  for (int k = 0; k < kPPT; k++) {
    if (vid[k] >= 0) {
      int pos = atomicAdd(&s_off[vid[k]], 1);
      s_pack[pos] = ((unsigned)vid[k] << 20) | (unsigned)pt[k];
    }
  }
  __syncthreads();

  // ---- flat-run gather: group g owns voxels STARTING in [16g, 16g+16) ----
  const int grp = tid >> 3;               // 0..127
  const int gl  = tid & 7;                // channel quad
  const size_t chOff = (size_t)gl * 4;
  float m0 = -FLT_MAX, m1 = -FLT_MAX, m2 = -FLT_MAX, m3 = -FLT_MAX;

  {
    const int p0 = grp * kGPW;
    if (p0 < npts) {
      const int p1 = min(p0 + kGPW, npts);
      const int v0 = (int)(s_pack[p0] >> 20);
      // skip head run continuing from previous window (s_off[v] = run END)
      int s = p0;
      if (p0 > 0 && (int)(s_pack[p0 - 1] >> 20) == v0) s = s_off[v0];
      // end of the run containing the window's last position
      const int vend = (int)(s_pack[p1 - 1] >> 20);
      const int pend = s_off[vend];  // if head run covers window: pend==s

      int curv = -1;
      float rin = 1.0f;
      float a0 = 0.f, a1 = 0.f, a2 = 0.f, a3 = 0.f;
      for (int base = s; base < pend; base += 8) {
        // pad guarantees in-bounds: ALL 8 reads/loads unconditional, no clamps
        const unsigned w0 = s_pack[base + 0], w1 = s_pack[base + 1],
                       w2 = s_pack[base + 2], w3 = s_pack[base + 3],
                       w4 = s_pack[base + 4], w5 = s_pack[base + 5],
                       w6 = s_pack[base + 6], w7 = s_pack[base + 7];
        const float4 f0 = *reinterpret_cast<const float4*>(
            &feats[(size_t)(w0 & 0xFFFFFu) * kC + chOff]);
        const float4 f1 = *reinterpret_cast<const float4*>(
            &feats[(size_t)(w1 & 0xFFFFFu) * kC + chOff]);
        const float4 f2 = *reinterpret_cast<const float4*>(
            &feats[(size_t)(w2 & 0xFFFFFu) * kC + chOff]);
        const float4 f3 = *reinterpret_cast<const float4*>(
            &feats[(size_t)(w3 & 0xFFFFFu) * kC + chOff]);
        const float4 f4 = *reinterpret_cast<const float4*>(
            &feats[(size_t)(w4 & 0xFFFFFu) * kC + chOff]);
        const float4 f5 = *reinterpret_cast<const float4*>(
            &feats[(size_t)(w5 & 0xFFFFFu) * kC + chOff]);
        const float4 f6 = *reinterpret_cast<const float4*>(
            &feats[(size_t)(w6 & 0xFFFFFu) * kC + chOff]);
        const float4 f7 = *reinterpret_cast<const float4*>(
            &feats[(size_t)(w7 & 0xFFFFFu) * kC + chOff]);
        const int m = pend - base;
#define PG_ACC(K, WK, FK)                                                  \
        if (m > K) {                                                       \
          const int vv = (int)(WK >> 20);                                  \
          if (vv != curv) {                                                \
            if (curv >= 0) {                                               \
              m0 = fmaxf(m0, a0 * rin); m1 = fmaxf(m1, a1 * rin);          \
              m2 = fmaxf(m2, a2 * rin); m3 = fmaxf(m3, a3 * rin);          \
            }                                                              \
            curv = vv; rin = s_rinv[vv];                                   \
            a0 = FK.x; a1 = FK.y; a2 = FK.z; a3 = FK.w;                    \
          } else {                                                         \
            a0 += FK.x; a1 += FK.y; a2 += FK.z; a3 += FK.w;                \
          }                                                                \
        }
        PG_ACC(0, w0, f0) PG_ACC(1, w1, f1) PG_ACC(2, w2, f2)
        PG_ACC(3, w3, f3) PG_ACC(4, w4, f4) PG_ACC(5, w5, f5)
        PG_ACC(6, w6, f6) PG_ACC(7, w7, f7)
#undef PG_ACC
      }
      if (curv >= 0) {
        m0 = fmaxf(m0, a0 * rin); m1 = fmaxf(m1, a1 * rin);
        m2 = fmaxf(m2, a2 * rin); m3 = fmaxf(m3, a3 * rin);
      }
    }
  }

  // reduce across the 8 groups within the wave (stride 8,16,32)
#pragma unroll
  for (int o = 8; o < 64; o <<= 1) {
    m0 = fmaxf(m0, __shfl_down(m0, o));
    m1 = fmaxf(m1, __shfl_down(m1, o));
    m2 = fmaxf(m2, __shfl_down(m2, o));
    m3 = fmaxf(m3, __shfl_down(m3, o));
  }
  if (lane < 8) {
    float* r = &s_redmax[wave * kC + lane * 4];
    r[0] = m0; r[1] = m1; r[2] = m2; r[3] = m3;
  }
  __syncthreads();
  if (tid < kC) {
    float mm = s_redmax[tid];
    for (int w = 1; w < kW; w++) mm = fmaxf(mm, s_redmax[w * kC + tid]);
    s_redmax[tid] = mm;
  }
  __syncthreads();

  // ---- score ----
  if (tid == 0) {
    float acc = bias[0];
    for (int j = 0; j < kC; j++) acc += s_redmax[j] * W[j];
    out[c] = acc;
  }
}

extern "C" void kernel_launch(void* const* d_in, const int* in_sizes, int n_in,
                              void* d_out, int out_size, void* d_ws,
                              size_t ws_size, hipStream_t stream) {
  const float* feats  = (const float*)d_in[0];
  const float* coords = (const float*)d_in[1];
  const float* W      = (const float*)d_in[2];
  const float* bias   = (const float*)d_in[3];
  const float* rand3  = (const float*)d_in[4];
  const int* cidx     = (const int*)d_in[5];
  const int* coff     = (const int*)d_in[6];
  float* out          = (float*)d_out;

  int nC = in_sizes[6] - 1;
  pg_kernel<<<nC, kBLK, 0, stream>>>(feats, coords, W, bias, rand3, cidx, coff,
                                     out);
}

// Round 9
// 44.200 us; speedup vs baseline: 1.0448x; 1.0448x over previous
//
#include <hip/hip_runtime.h>
#include <float.h>

// PointGroup FINAL (= R7, best measured at 44.3 µs; R8's micro-trims
// regressed 4% and are reverted).
// Structure: one 1024-thread block per cluster.
//   A) gather coords -> block reduce sum/min/max -> cluster scale/offset
//   B) per-point voxel id (reference FP op order)
//   C) LDS counting-sort by voxel (count -> scan -> scatter), pack
//      (vid<<20)|pid into one u32 per sorted position
//   D) flat-run gather: each 8-lane group owns runs starting in its 16-pt
//      window; 8 independent global_load_dwordx4 in flight per lane;
//      per-voxel mean via precomputed 1/cnt table; running max in regs
//   E) block max-reduce -> dot with W -> one score per cluster.
// Ceiling evidence: FETCH=117MB compulsory, occupancy 79% (max), MLP-depth
// neutral (R6), VALU trims exhausted (R7/R8) -> random-128B-row gather
// pattern ceiling (~2.7 TB/s effective vs 6.9 TB/s streaming on this chip).

constexpr int kC    = 32;
constexpr int kFS   = 14;
constexpr int kNVOX = kFS * kFS * kFS;  // 2744
constexpr int kBLK  = 1024;
constexpr int kW    = kBLK / 64;        // 16 waves
constexpr int kPPT  = 2;                // points per thread (2048/1024)
constexpr int kPTS  = 2048;
constexpr int kCPT  = (kNVOX + kBLK - 1) / kBLK;  // 3 voxels per thread (scan)
constexpr int kGPW  = 16;               // points-window per group

__device__ inline float wsum(float v) {
#pragma unroll
  for (int o = 32; o; o >>= 1) v += __shfl_down(v, o);
  return v;
}
__device__ inline float wmin(float v) {
#pragma unroll
  for (int o = 32; o; o >>= 1) v = fminf(v, __shfl_down(v, o));
  return v;
}
__device__ inline float wmax(float v) {
#pragma unroll
  for (int o = 32; o; o >>= 1) v = fmaxf(v, __shfl_down(v, o));
  return v;
}

__global__ __launch_bounds__(kBLK, 8) void pg_kernel(
    const float* __restrict__ feats, const float* __restrict__ coords,
    const float* __restrict__ W, const float* __restrict__ bias,
    const float* __restrict__ rand3, const int* __restrict__ cidx,
    const int* __restrict__ coff, float* __restrict__ out) {
  __shared__ int s_cnt[kNVOX];
  __shared__ int s_off[kNVOX];       // after scatter: per-voxel END position
  __shared__ float s_rinv[kNVOX];    // 1/cnt per voxel
  __shared__ unsigned s_pack[kPTS];  // (vid<<20) | pid per sorted position
  __shared__ float s_red[kW * 9];
  __shared__ float s_redmax[kW * kC];
  __shared__ float s_bcast[7];
  __shared__ int s_wt[kW];

  const int c = blockIdx.x;
  const int tid = threadIdx.x;
  const int lane = tid & 63, wave = tid >> 6;
  const int start = coff[c], end = coff[c + 1];
  const int npts = end - start;

  // ---- Phase A: gather coords, reduce sum/min/max ----
  int pt[kPPT];
  float px[kPPT], py[kPPT], pz[kPPT];
  float sx = 0.f, sy = 0.f, sz = 0.f;
  float mnx = FLT_MAX, mny = FLT_MAX, mnz = FLT_MAX;
  float mxx = -FLT_MAX, mxy = -FLT_MAX, mxz = -FLT_MAX;
#pragma unroll
  for (int k = 0; k < kPPT; k++) {
    int i = start + tid + k * kBLK;
    if (i < end) {
      int p = cidx[2 * i + 1];
      pt[k] = p;
      float x = coords[3 * p + 0], y = coords[3 * p + 1], z = coords[3 * p + 2];
      px[k] = x; py[k] = y; pz[k] = z;
      sx += x; sy += y; sz += z;
      mnx = fminf(mnx, x); mny = fminf(mny, y); mnz = fminf(mnz, z);
      mxx = fmaxf(mxx, x); mxy = fmaxf(mxy, y); mxz = fmaxf(mxz, z);
    } else {
      pt[k] = -1;
    }
  }
  sx = wsum(sx); sy = wsum(sy); sz = wsum(sz);
  mnx = wmin(mnx); mny = wmin(mny); mnz = wmin(mnz);
  mxx = wmax(mxx); mxy = wmax(mxy); mxz = wmax(mxz);
  if (lane == 0) {
    float* r = &s_red[wave * 9];
    r[0] = sx; r[1] = sy; r[2] = sz;
    r[3] = mnx; r[4] = mny; r[5] = mnz;
    r[6] = mxx; r[7] = mxy; r[8] = mxz;
  }
  __syncthreads();
  if (tid == 0) {
    float Sx = s_red[0], Sy = s_red[1], Sz = s_red[2];
    float Mnx = s_red[3], Mny = s_red[4], Mnz = s_red[5];
    float Mxx = s_red[6], Mxy = s_red[7], Mxz = s_red[8];
    for (int w = 1; w < kW; w++) {
      const float* r = &s_red[w * 9];
      Sx += r[0]; Sy += r[1]; Sz += r[2];
      Mnx = fminf(Mnx, r[3]); Mny = fminf(Mny, r[4]); Mnz = fminf(Mnz, r[5]);
      Mxx = fmaxf(Mxx, r[6]); Mxy = fmaxf(Mxy, r[7]); Mxz = fmaxf(Mxz, r[8]);
    }
    float n = (float)npts;
    float cmx = Sx / n, cmy = Sy / n, cmz = Sz / n;
    float cminx = Mnx - cmx, cminy = Mny - cmy, cminz = Mnz - cmz;
    float cmaxx = Mxx - cmx, cmaxy = Mxy - cmy, cmaxz = Mxz - cmz;
    float r0 = (cmaxx - cminx) / 14.0f;
    float r1 = (cmaxy - cminy) / 14.0f;
    float r2 = (cmaxz - cminz) / 14.0f;
    float cs = 1.0f / fmaxf(fmaxf(r0, r1), r2) - 0.01f;
    cs = fminf(cs, 50.0f);
    float r3x = rand3[0], r3y = rand3[1], r3z = rand3[2];
    float mn0 = cminx * cs, mx0 = cmaxx * cs, b0 = mx0 - mn0;
    float mn1 = cminy * cs, mx1 = cmaxy * cs, b1 = mx1 - mn1;
    float mn2 = cminz * cs, mx2 = cmaxz * cs, b2 = mx2 - mn2;
    float ox = -mn0 + fmaxf(14.0f - b0 - 0.001f, 0.0f) * r3x +
               fminf(14.0f - b0 + 0.001f, 0.0f) * r3x;
    float oy = -mn1 + fmaxf(14.0f - b1 - 0.001f, 0.0f) * r3y +
               fminf(14.0f - b1 + 0.001f, 0.0f) * r3y;
    float oz = -mn2 + fmaxf(14.0f - b2 - 0.001f, 0.0f) * r3z +
               fminf(14.0f - b2 + 0.001f, 0.0f) * r3z;
    s_bcast[0] = cmx; s_bcast[1] = cmy; s_bcast[2] = cmz;
    s_bcast[3] = cs;
    s_bcast[4] = ox; s_bcast[5] = oy; s_bcast[6] = oz;
  }
  __syncthreads();
  const float cmx = s_bcast[0], cmy = s_bcast[1], cmz = s_bcast[2];
  const float cs = s_bcast[3];
  const float ox = s_bcast[4], oy = s_bcast[5], oz = s_bcast[6];

  // ---- voxel ids (reference FP op order) ----
  int vid[kPPT];
#pragma unroll
  for (int k = 0; k < kPPT; k++) {
    if (pt[k] >= 0) {
      float tx = (px[k] - cmx) * cs + ox;
      float ty = (py[k] - cmy) * cs + oy;
      float tz = (pz[k] - cmz) * cs + oz;
      int vx = min(kFS - 1, max(0, (int)floorf(tx)));
      int vy = min(kFS - 1, max(0, (int)floorf(ty)));
      int vz = min(kFS - 1, max(0, (int)floorf(tz)));
      vid[k] = (vx * kFS + vy) * kFS + vz;
    } else {
      vid[k] = -1;
    }
  }

  // ---- counting sort: counts ----
  for (int v = tid; v < kNVOX; v += kBLK) s_cnt[v] = 0;
  __syncthreads();
#pragma unroll
  for (int k = 0; k < kPPT; k++)
    if (vid[k] >= 0) atomicAdd(&s_cnt[vid[k]], 1);
  __syncthreads();

  // ---- exclusive prefix scan over s_cnt -> s_off; also fill s_rinv ----
  {
    const int base = tid * kCPT;
    int local[kCPT];
    int sum = 0;
#pragma unroll
    for (int j = 0; j < kCPT; j++) {
      int v = base + j;
      int x = (v < kNVOX) ? s_cnt[v] : 0;
      if (v < kNVOX) s_rinv[v] = (x > 0) ? (1.0f / (float)x) : 0.0f;
      local[j] = sum;
      sum += x;
    }
    int inc = sum;
#pragma unroll
    for (int o = 1; o < 64; o <<= 1) {
      int t = __shfl_up(inc, o);
      if (lane >= o) inc += t;
    }
    if (lane == 63) s_wt[wave] = inc;
    __syncthreads();
    if (tid == 0) {
      int a = 0;
      for (int w = 0; w < kW; w++) {
        int t = s_wt[w];
        s_wt[w] = a;
        a += t;
      }
    }
    __syncthreads();
    const int texcl = s_wt[wave] + inc - sum;
#pragma unroll
    for (int j = 0; j < kCPT; j++) {
      int v = base + j;
      if (v < kNVOX) s_off[v] = texcl + local[j];
    }
  }
  __syncthreads();

  // ---- scatter (s_off becomes per-voxel END); pack (vid<<20)|pid ----
#pragma unroll
  for (int k = 0; k < kPPT; k++) {
    if (vid[k] >= 0) {
      int pos = atomicAdd(&s_off[vid[k]], 1);
      s_pack[pos] = ((unsigned)vid[k] << 20) | (unsigned)pt[k];
    }
  }
  __syncthreads();

  // ---- flat-run gather: group g owns voxels STARTING in [16g, 16g+16) ----
  const int grp = tid >> 3;               // 0..127
  const int gl  = tid & 7;                // channel quad
  const size_t chOff = (size_t)gl * 4;
  float m0 = -FLT_MAX, m1 = -FLT_MAX, m2 = -FLT_MAX, m3 = -FLT_MAX;

  {
    const int p0 = grp * kGPW;
    if (p0 < npts) {
      const int p1 = min(p0 + kGPW, npts);
      const int v0 = (int)(s_pack[p0] >> 20);
      // skip head run continuing from previous window (s_off[v] = run END)
      int s = p0;
      if (p0 > 0 && (int)(s_pack[p0 - 1] >> 20) == v0) s = s_off[v0];
      // end of the run containing the window's last position
      const int vend = (int)(s_pack[p1 - 1] >> 20);
      const int pend = s_off[vend];  // if head run covers window: pend==s

      int curv = -1;
      float rin = 1.0f;
      float a0 = 0.f, a1 = 0.f, a2 = 0.f, a3 = 0.f;
      for (int base = s; base < pend; base += 8) {
        // clamped sorted positions -> ALL 8 loads unconditional & independent
        const int j0 = base + 0, j1 = min(base + 1, pend - 1),
                  j2 = min(base + 2, pend - 1), j3 = min(base + 3, pend - 1),
                  j4 = min(base + 4, pend - 1), j5 = min(base + 5, pend - 1),
                  j6 = min(base + 6, pend - 1), j7 = min(base + 7, pend - 1);
        const unsigned w0 = s_pack[j0], w1 = s_pack[j1], w2 = s_pack[j2],
                       w3 = s_pack[j3], w4 = s_pack[j4], w5 = s_pack[j5],
                       w6 = s_pack[j6], w7 = s_pack[j7];
        const float4 f0 = *reinterpret_cast<const float4*>(
            &feats[(size_t)(w0 & 0xFFFFFu) * kC + chOff]);
        const float4 f1 = *reinterpret_cast<const float4*>(
            &feats[(size_t)(w1 & 0xFFFFFu) * kC + chOff]);
        const float4 f2 = *reinterpret_cast<const float4*>(
            &feats[(size_t)(w2 & 0xFFFFFu) * kC + chOff]);
        const float4 f3 = *reinterpret_cast<const float4*>(
            &feats[(size_t)(w3 & 0xFFFFFu) * kC + chOff]);
        const float4 f4 = *reinterpret_cast<const float4*>(
            &feats[(size_t)(w4 & 0xFFFFFu) * kC + chOff]);
        const float4 f5 = *reinterpret_cast<const float4*>(
            &feats[(size_t)(w5 & 0xFFFFFu) * kC + chOff]);
        const float4 f6 = *reinterpret_cast<const float4*>(
            &feats[(size_t)(w6 & 0xFFFFFu) * kC + chOff]);
        const float4 f7 = *reinterpret_cast<const float4*>(
            &feats[(size_t)(w7 & 0xFFFFFu) * kC + chOff]);
        const int m = pend - base;
#define PG_ACC(K, WK, FK)                                                  \
        if (m > K) {                                                       \
          const int vv = (int)(WK >> 20);                                  \
          if (vv != curv) {                                                \
            if (curv >= 0) {                                               \
              m0 = fmaxf(m0, a0 * rin); m1 = fmaxf(m1, a1 * rin);          \
              m2 = fmaxf(m2, a2 * rin); m3 = fmaxf(m3, a3 * rin);          \
            }                                                              \
            curv = vv; rin = s_rinv[vv];                                   \
            a0 = FK.x; a1 = FK.y; a2 = FK.z; a3 = FK.w;                    \
          } else {                                                         \
            a0 += FK.x; a1 += FK.y; a2 += FK.z; a3 += FK.w;                \
          }                                                                \
        }
        PG_ACC(0, w0, f0) PG_ACC(1, w1, f1) PG_ACC(2, w2, f2)
        PG_ACC(3, w3, f3) PG_ACC(4, w4, f4) PG_ACC(5, w5, f5)
        PG_ACC(6, w6, f6) PG_ACC(7, w7, f7)
#undef PG_ACC
      }
      if (curv >= 0) {
        m0 = fmaxf(m0, a0 * rin); m1 = fmaxf(m1, a1 * rin);
        m2 = fmaxf(m2, a2 * rin); m3 = fmaxf(m3, a3 * rin);
      }
    }
  }

  // reduce across the 8 groups within the wave (stride 8,16,32)
#pragma unroll
  for (int o = 8; o < 64; o <<= 1) {
    m0 = fmaxf(m0, __shfl_down(m0, o));
    m1 = fmaxf(m1, __shfl_down(m1, o));
    m2 = fmaxf(m2, __shfl_down(m2, o));
    m3 = fmaxf(m3, __shfl_down(m3, o));
  }
  if (lane < 8) {
    float* r = &s_redmax[wave * kC + lane * 4];
    r[0] = m0; r[1] = m1; r[2] = m2; r[3] = m3;
  }
  __syncthreads();
  if (tid < kC) {
    float mm = s_redmax[tid];
    for (int w = 1; w < kW; w++) mm = fmaxf(mm, s_redmax[w * kC + tid]);
    s_redmax[tid] = mm;
  }
  __syncthreads();

  // ---- score ----
  if (tid == 0) {
    float acc = bias[0];
    for (int j = 0; j < kC; j++) acc += s_redmax[j] * W[j];
    out[c] = acc;
  }
}

extern "C" void kernel_launch(void* const* d_in, const int* in_sizes, int n_in,
                              void* d_out, int out_size, void* d_ws,
                              size_t ws_size, hipStream_t stream) {
  const float* feats  = (const float*)d_in[0];
  const float* coords = (const float*)d_in[1];
  const float* W      = (const float*)d_in[2];
  const float* bias   = (const float*)d_in[3];
  const float* rand3  = (const float*)d_in[4];
  const int* cidx     = (const int*)d_in[5];
  const int* coff     = (const int*)d_in[6];
  float* out          = (float*)d_out;

  int nC = in_sizes[6] - 1;
  pg_kernel<<<nC, kBLK, 0, stream>>>(feats, coords, W, bias, rand3, cidx, coff,
                                     out);
}